// Round 5
// baseline (6466.160 us; speedup 1.0000x reference)
//
#include <hip/hip_runtime.h>
#include <hip/hip_bf16.h>

// EA-LSTM persistent kernel for MI355X (gfx950), round 5.
// B=128, T=2048, DYN=8, STAT=24, H=256, OUT=1.
// 16 WGs x 512 threads; WG owns 8 batch rows (M=16 MFMA tile, rows 8..15 pad).
// Wave w owns channels [w*32, w*32+32) of every gate.
// Redistribution: after MFMAs, __shfl_xor(acc,32) hands r={2,3} of the valid
// accs to the pad-row lanes (lg>=2), so EVERY lane does 4 gate-sets (half of R4).
// Weights: f,g recurrent + x-projections in regs (160 VGPR); o gate in LDS.
// Double-buffered A tile (h,x), ONE barrier per step.

#define T_LEN 2048
#define HD 256

typedef __attribute__((ext_vector_type(8))) short bf16x8;
typedef __attribute__((ext_vector_type(4))) float f32x4;

#define LOG2E 1.4426950408889634f

__device__ __forceinline__ short f2bf(float f) {
  unsigned u = __float_as_uint(f);
  unsigned r = (u + 0x7fffu + ((u >> 16) & 1u)) >> 16;
  return (short)r;
}

__device__ __forceinline__ bf16x8 loadw8(const float* p) {
  bf16x8 r;
#pragma unroll
  for (int i = 0; i < 8; ++i) r[i] = f2bf(p[i]);
  return r;
}

__device__ __forceinline__ float sigm(float x) {
  float e = __builtin_amdgcn_exp2f(-LOG2E * x);
  return __builtin_amdgcn_rcpf(1.0f + e);
}

// clamp-free tanh: 1 - 2/(e^{2x}+1); saturates to +/-1, NaN-free.
__device__ __forceinline__ float tanh_(float x) {
  float e = __builtin_amdgcn_exp2f((2.0f * LOG2E) * x);
  return 1.0f - 2.0f * __builtin_amdgcn_rcpf(e + 1.0f);
}

// A tile: 16 rows x 296 cols bf16 (0..255 = h, 256..287 = x_t, 288+ pad).
#define ASTR 296
#define ABUF (16 * ASTR)

__global__ __launch_bounds__(512, 2) void ealstm_kernel(
    const float* __restrict__ x, const float* __restrict__ c0, const float* __restrict__ h0,
    const float* __restrict__ Wi, const float* __restrict__ bi,
    const float* __restrict__ Wfx, const float* __restrict__ bfx,
    const float* __restrict__ Wfh, const float* __restrict__ bfh,
    const float* __restrict__ Wgx, const float* __restrict__ bgx,
    const float* __restrict__ Wgh, const float* __restrict__ bgh,
    const float* __restrict__ Wox, const float* __restrict__ box_,
    const float* __restrict__ Woh, const float* __restrict__ boh,
    const float* __restrict__ Wout, const float* __restrict__ bout,
    float* __restrict__ out)
{
  __shared__ __attribute__((aligned(16))) short A_sh[2 * ABUF];        // 18944 B
  __shared__ __attribute__((aligned(16))) short Bo_sh[8 * 16 * 512];   // 131072 B
  __shared__ float out_part[2][8][8];                                  // 512 B

  const int tid = threadIdx.x;
  const int w   = tid >> 6;
  const int l   = tid & 63;
  const int lr  = l & 15;
  const int lg  = l >> 4;
  const int n0  = w * 32;
  const int wg  = blockIdx.x;
  // activation-row assignment after redistribution:
  // lg0 -> rows {0,1}, lg1 -> {4,5}, lg2 -> {2,3}, lg3 -> {6,7}
  const int rowA = (lg & 1) * 4 + (lg >> 1) * 2;
  const bool useOwn = (lg < 2);  // own acc r={0,1} vs swapped r={2,3}

  // ---- register-resident weights: f,g recurrent + all x-projections ----
  bf16x8 Bf[8][2], Bg[8][2], Bx[4][2];
#pragma unroll
  for (int ks = 0; ks < 8; ++ks) {
#pragma unroll
    for (int nt = 0; nt < 2; ++nt) {
      const int n = n0 + nt * 16 + lr;
      const int k = ks * 32 + lg * 8;
      Bf[ks][nt] = loadw8(Wfh + n * HD + k);
      Bg[ks][nt] = loadw8(Wgh + n * HD + k);
    }
  }
  {
    bf16x8 z = (bf16x8)(short)0;
    const float* WxArr[3] = {Wfx, Wgx, Wox};
#pragma unroll
    for (int nt = 0; nt < 2; ++nt) {
      const int n = n0 + nt * 16 + lr;
#pragma unroll
      for (int g = 0; g < 3; ++g) {
        Bx[g][nt] = (lg == 0) ? loadw8(WxArr[g] + n * 8) : z;
      }
      Bx[3][nt] = (lg >= 1) ? loadw8(Wi + n * 24 + (lg - 1) * 8) : z;
    }
  }

  // ---- LDS-resident: o-gate, all 8 K-steps ----
  short* bo = Bo_sh + w * (16 * 512);
#pragma unroll
  for (int ks = 0; ks < 8; ++ks) {
#pragma unroll
    for (int nt = 0; nt < 2; ++nt) {
      const int n = n0 + nt * 16 + lr;
      bf16x8 fr = loadw8(Woh + n * HD + ks * 32 + lg * 8);
      *reinterpret_cast<bf16x8*>(bo + (ks * 2 + nt) * 512 + l * 8) = fr;
    }
  }

  // ---- biases, Wout, c-state (per-lane: 2 rows x 2 nt) ----
  float bias[4][2], woutv[2];
  float cst[2][2];  // [nt][rsel]
#pragma unroll
  for (int nt = 0; nt < 2; ++nt) {
    const int n = n0 + nt * 16 + lr;
    bias[0][nt] = bfx[n] + bfh[n];
    bias[1][nt] = bgx[n] + bgh[n];
    bias[2][nt] = box_[n] + boh[n];
    bias[3][nt] = bi[n];
    woutv[nt] = Wout[n];
    cst[nt][0] = c0[n];
    cst[nt][1] = c0[n];
  }
  const float boutv = bout[0];

  // ---- zero both A buffers, then stage h0 (rows 0..7) and x_0 ----
  for (int idx = tid; idx < 2 * ABUF; idx += 512) A_sh[idx] = 0;
  __syncthreads();
  for (int idx = tid; idx < 8 * 256; idx += 512) {
    A_sh[(idx >> 8) * ASTR + (idx & 255)] = f2bf(h0[idx & 255]);
  }
  if (tid < 256) {
    const int row = tid >> 5, k = tid & 31;
    A_sh[row * ASTR + 256 + k] = f2bf(x[((size_t)(wg * 8 + row) * T_LEN) * 32 + k]);
  }
  __syncthreads();

  const float* xp = x + (size_t)(wg * 8 + ((tid >> 5) & 7)) * T_LEN * 32 + (tid & 31);
  const int akoff = lg * 8;

  for (int t = 0; t < T_LEN; ++t) {
    const int cur = t & 1;
    const short* ArowC = A_sh + cur * ABUF + lr * ASTR;
    short* Anxt = A_sh + (cur ^ 1) * ABUF;

    // finalize previous step's output (hidden under this step's MFMA phase)
    if (t > 0 && w == 0 && l < 8) {
      float s = boutv;
#pragma unroll
      for (int ww = 0; ww < 8; ++ww) s += out_part[cur ^ 1][l][ww];
      out[(size_t)(wg * 8 + l) * T_LEN + (t - 1)] = s;
    }

    // prefetch x_{t+1} (rows 0..7)
    float xval = 0.0f;
    if (tid < 256) {
      const int tn = (t + 1 < T_LEN) ? (t + 1) : (T_LEN - 1);
      xval = xp[(size_t)tn * 32];
    }

    // acc init with biases
    f32x4 acc[4][2];
#pragma unroll
    for (int g = 0; g < 4; ++g) {
#pragma unroll
      for (int nt = 0; nt < 2; ++nt) {
        f32x4 v; v[0] = bias[g][nt]; v[1] = bias[g][nt]; v[2] = bias[g][nt]; v[3] = bias[g][nt];
        acc[g][nt] = v;
      }
    }

    // ---- FG K-loop: register-weight MFMAs ----
#pragma unroll
    for (int ks = 0; ks < 8; ++ks) {
      const bf16x8 a = *reinterpret_cast<const bf16x8*>(ArowC + ks * 32 + akoff);
      acc[0][0] = __builtin_amdgcn_mfma_f32_16x16x32_bf16(a, Bf[ks][0], acc[0][0], 0, 0, 0);
      acc[0][1] = __builtin_amdgcn_mfma_f32_16x16x32_bf16(a, Bf[ks][1], acc[0][1], 0, 0, 0);
      acc[1][0] = __builtin_amdgcn_mfma_f32_16x16x32_bf16(a, Bg[ks][0], acc[1][0], 0, 0, 0);
      acc[1][1] = __builtin_amdgcn_mfma_f32_16x16x32_bf16(a, Bg[ks][1], acc[1][1], 0, 0, 0);
    }

    // ---- i/x MFMA burst ----
    {
      const bf16x8 axv = *reinterpret_cast<const bf16x8*>(ArowC + 256 + akoff);
      acc[3][0] = __builtin_amdgcn_mfma_f32_16x16x32_bf16(axv, Bx[3][0], acc[3][0], 0, 0, 0);
      acc[3][1] = __builtin_amdgcn_mfma_f32_16x16x32_bf16(axv, Bx[3][1], acc[3][1], 0, 0, 0);
      acc[0][0] = __builtin_amdgcn_mfma_f32_16x16x32_bf16(axv, Bx[0][0], acc[0][0], 0, 0, 0);
      acc[0][1] = __builtin_amdgcn_mfma_f32_16x16x32_bf16(axv, Bx[0][1], acc[0][1], 0, 0, 0);
      acc[1][0] = __builtin_amdgcn_mfma_f32_16x16x32_bf16(axv, Bx[1][0], acc[1][0], 0, 0, 0);
      acc[1][1] = __builtin_amdgcn_mfma_f32_16x16x32_bf16(axv, Bx[1][1], acc[1][1], 0, 0, 0);
      acc[2][0] = __builtin_amdgcn_mfma_f32_16x16x32_bf16(axv, Bx[2][0], acc[2][0], 0, 0, 0);
      acc[2][1] = __builtin_amdgcn_mfma_f32_16x16x32_bf16(axv, Bx[2][1], acc[2][1], 0, 0, 0);
    }

    // ---- redistribute f,g,i accs: lane l <-> l^32 (issues early, overlaps O-loop) ----
    float pf[2][2], pg[2][2], pi[2][2];
#pragma unroll
    for (int nt = 0; nt < 2; ++nt) {
#pragma unroll
      for (int rs = 0; rs < 2; ++rs) {
        const float sf_ = __shfl_xor(acc[0][nt][2 + rs], 32, 64);
        const float sg_ = __shfl_xor(acc[1][nt][2 + rs], 32, 64);
        const float si_ = __shfl_xor(acc[3][nt][2 + rs], 32, 64);
        pf[nt][rs] = useOwn ? acc[0][nt][rs] : sf_;
        pg[nt][rs] = useOwn ? acc[1][nt][rs] : sg_;
        pi[nt][rs] = useOwn ? acc[3][nt][rs] : si_;
      }
    }

    // ---- O K-loop: LDS-weight MFMAs (VALU c-path below overlaps in scheduler) ----
#pragma unroll
    for (int ks = 0; ks < 8; ++ks) {
      const bf16x8 a  = *reinterpret_cast<const bf16x8*>(ArowC + ks * 32 + akoff);
      const bf16x8 b0 = *reinterpret_cast<const bf16x8*>(bo + (ks * 2 + 0) * 512 + l * 8);
      const bf16x8 b1 = *reinterpret_cast<const bf16x8*>(bo + (ks * 2 + 1) * 512 + l * 8);
      acc[2][0] = __builtin_amdgcn_mfma_f32_16x16x32_bf16(a, b0, acc[2][0], 0, 0, 0);
      acc[2][1] = __builtin_amdgcn_mfma_f32_16x16x32_bf16(a, b1, acc[2][1], 0, 0, 0);
    }

    // ---- c-path (4 sets/lane): f,g,i -> c -> tanh(c) ----
    float tcv[2][2];
#pragma unroll
    for (int nt = 0; nt < 2; ++nt) {
#pragma unroll
      for (int rs = 0; rs < 2; ++rs) {
        const float sf = sigm(pf[nt][rs]);
        const float tg = tanh_(pg[nt][rs]);
        const float si = sigm(pi[nt][rs]);
        const float c  = sf * cst[nt][rs] + si * tg;
        cst[nt][rs] = c;
        tcv[nt][rs] = tanh_(c);
      }
    }

    // ---- redistribute o accs, then o-path tail ----
    short hpk[2][2];
    float po[2]; po[0] = 0.f; po[1] = 0.f;
#pragma unroll
    for (int nt = 0; nt < 2; ++nt) {
#pragma unroll
      for (int rs = 0; rs < 2; ++rs) {
        const float so_sw = __shfl_xor(acc[2][nt][2 + rs], 32, 64);
        const float pov   = useOwn ? acc[2][nt][rs] : so_sw;
        const float so    = sigm(pov);
        const float hv    = so * tcv[nt][rs];
        hpk[nt][rs] = f2bf(hv);
        po[rs] += so * woutv[nt];
      }
    }

    // h-writes into ALTERNATE buffer (rows rowA, rowA+1)
#pragma unroll
    for (int nt = 0; nt < 2; ++nt) {
#pragma unroll
      for (int rs = 0; rs < 2; ++rs) {
        Anxt[(rowA + rs) * ASTR + (n0 + nt * 16 + lr)] = hpk[nt][rs];
      }
    }
    if (tid < 256) Anxt[((tid >> 5) & 7) * ASTR + 256 + (tid & 31)] = f2bf(xval);

    // po reduce over the 16 lr-lanes, one slot per (row, wave)
#pragma unroll
    for (int rs = 0; rs < 2; ++rs) {
#pragma unroll
      for (int mk = 1; mk < 16; mk <<= 1) {
        po[rs] += __shfl_xor(po[rs], mk, 64);
      }
    }
    if (lr == 0) {
      out_part[cur][rowA + 0][w] = po[0];
      out_part[cur][rowA + 1][w] = po[1];
    }

    __syncthreads();  // single per-step barrier
  }

  // final output
  if (w == 0 && l < 8) {
    float s = boutv;
#pragma unroll
    for (int ww = 0; ww < 8; ++ww) s += out_part[(T_LEN - 1) & 1][l][ww];
    out[(size_t)(wg * 8 + l) * T_LEN + (T_LEN - 1)] = s;
  }
}

extern "C" void kernel_launch(void* const* d_in, const int* in_sizes, int n_in,
                              void* d_out, int out_size, void* d_ws, size_t ws_size,
                              hipStream_t stream) {
  const float* x    = (const float*)d_in[0];
  const float* c0   = (const float*)d_in[1];
  const float* h0   = (const float*)d_in[2];
  const float* Wi   = (const float*)d_in[3];
  const float* bi   = (const float*)d_in[4];
  const float* Wfx  = (const float*)d_in[5];
  const float* bfx  = (const float*)d_in[6];
  const float* Wfh  = (const float*)d_in[7];
  const float* bfh  = (const float*)d_in[8];
  const float* Wgx  = (const float*)d_in[9];
  const float* bgx  = (const float*)d_in[10];
  const float* Wgh  = (const float*)d_in[11];
  const float* bgh  = (const float*)d_in[12];
  const float* Wox  = (const float*)d_in[13];
  const float* box_ = (const float*)d_in[14];
  const float* Woh  = (const float*)d_in[15];
  const float* boh  = (const float*)d_in[16];
  const float* Wout = (const float*)d_in[17];
  const float* bout = (const float*)d_in[18];

  ealstm_kernel<<<dim3(16), dim3(512), 0, stream>>>(
      x, c0, h0, Wi, bi, Wfx, bfx, Wfh, bfh,
      Wgx, bgx, Wgh, bgh, Wox, box_, Woh, boh, Wout, bout,
      (float*)d_out);
}

// Round 6
// 4060.766 us; speedup vs baseline: 1.5923x; 1.5923x over previous
//
#include <hip/hip_runtime.h>
#include <hip/hip_bf16.h>

// EA-LSTM persistent kernel for MI355X (gfx950), round 6.
// B=128, T=2048, DYN=8, STAT=24, H=256, OUT=1.
// 32 WGs x 512 threads; WG owns 4 batch rows. KEY: batch row b is staged at
// A-tile row 4b, so MFMA D-layout (row = lg*4 + r) puts the valid rows at
// r==0 of EVERY lane group -> each lane owns exactly 2 gate-sets (row = lg,
// ch = n0 + nt*16 + lr) with NO redistribution (no shuffles, no LDS scratch).
// Weights: f,g recurrent + x-projections in regs; o gate in LDS.
// Double-buffered A tile (h,x), ONE barrier per step.

#define T_LEN 2048
#define HD 256

typedef __attribute__((ext_vector_type(8))) short bf16x8;
typedef __attribute__((ext_vector_type(4))) float f32x4;

#define LOG2E 1.4426950408889634f

__device__ __forceinline__ short f2bf(float f) {
  unsigned u = __float_as_uint(f);
  unsigned r = (u + 0x7fffu + ((u >> 16) & 1u)) >> 16;
  return (short)r;
}

__device__ __forceinline__ bf16x8 loadw8(const float* p) {
  bf16x8 r;
#pragma unroll
  for (int i = 0; i < 8; ++i) r[i] = f2bf(p[i]);
  return r;
}

__device__ __forceinline__ float sigm(float x) {
  float e = __builtin_amdgcn_exp2f(-LOG2E * x);
  return __builtin_amdgcn_rcpf(1.0f + e);
}

// clamp-free tanh: 1 - 2/(e^{2x}+1); saturates to +/-1, NaN-free.
__device__ __forceinline__ float tanh_(float x) {
  float e = __builtin_amdgcn_exp2f((2.0f * LOG2E) * x);
  return 1.0f - 2.0f * __builtin_amdgcn_rcpf(e + 1.0f);
}

// A tile: 16 rows x 296 cols bf16 (0..255 = h, 256..287 = x_t, 288+ pad).
// Valid batch rows live at A-rows {0,4,8,12}; rows {1,2,3,5,...} stay zero.
#define ASTR 296
#define ABUF (16 * ASTR)

__global__ __launch_bounds__(512, 2) void ealstm_kernel(
    const float* __restrict__ x, const float* __restrict__ c0, const float* __restrict__ h0,
    const float* __restrict__ Wi, const float* __restrict__ bi,
    const float* __restrict__ Wfx, const float* __restrict__ bfx,
    const float* __restrict__ Wfh, const float* __restrict__ bfh,
    const float* __restrict__ Wgx, const float* __restrict__ bgx,
    const float* __restrict__ Wgh, const float* __restrict__ bgh,
    const float* __restrict__ Wox, const float* __restrict__ box_,
    const float* __restrict__ Woh, const float* __restrict__ boh,
    const float* __restrict__ Wout, const float* __restrict__ bout,
    float* __restrict__ out)
{
  __shared__ __attribute__((aligned(16))) short A_sh[2 * ABUF];        // 18944 B
  __shared__ __attribute__((aligned(16))) short Bo_sh[8 * 16 * 512];   // 131072 B
  __shared__ float out_part[2][4][8];                                  // 256 B

  const int tid = threadIdx.x;
  const int w   = tid >> 6;
  const int l   = tid & 63;
  const int lr  = l & 15;
  const int lg  = l >> 4;     // after the A-row trick: activation row = lg
  const int n0  = w * 32;
  const int wg  = blockIdx.x; // 4-row batch block

  // ---- register-resident weights: f,g recurrent + all x-projections ----
  bf16x8 Bf[8][2], Bg[8][2], Bx[4][2];
#pragma unroll
  for (int ks = 0; ks < 8; ++ks) {
#pragma unroll
    for (int nt = 0; nt < 2; ++nt) {
      const int n = n0 + nt * 16 + lr;
      const int k = ks * 32 + lg * 8;
      Bf[ks][nt] = loadw8(Wfh + n * HD + k);
      Bg[ks][nt] = loadw8(Wgh + n * HD + k);
    }
  }
  {
    bf16x8 z = (bf16x8)(short)0;
    const float* WxArr[3] = {Wfx, Wgx, Wox};
#pragma unroll
    for (int nt = 0; nt < 2; ++nt) {
      const int n = n0 + nt * 16 + lr;
#pragma unroll
      for (int g = 0; g < 3; ++g) {
        Bx[g][nt] = (lg == 0) ? loadw8(WxArr[g] + n * 8) : z;
      }
      Bx[3][nt] = (lg >= 1) ? loadw8(Wi + n * 24 + (lg - 1) * 8) : z;
    }
  }

  // ---- LDS-resident: o-gate, all 8 K-steps ----
  short* bo = Bo_sh + w * (16 * 512);
#pragma unroll
  for (int ks = 0; ks < 8; ++ks) {
#pragma unroll
    for (int nt = 0; nt < 2; ++nt) {
      const int n = n0 + nt * 16 + lr;
      bf16x8 fr = loadw8(Woh + n * HD + ks * 32 + lg * 8);
      *reinterpret_cast<bf16x8*>(bo + (ks * 2 + nt) * 512 + l * 8) = fr;
    }
  }

  // ---- biases, Wout, c-state (1 row x 2 nt per lane) ----
  float bias[4][2], woutv[2], cst[2];
#pragma unroll
  for (int nt = 0; nt < 2; ++nt) {
    const int n = n0 + nt * 16 + lr;
    bias[0][nt] = bfx[n] + bfh[n];
    bias[1][nt] = bgx[n] + bgh[n];
    bias[2][nt] = box_[n] + boh[n];
    bias[3][nt] = bi[n];
    woutv[nt] = Wout[n];
    cst[nt] = c0[n];
  }
  const float boutv = bout[0];

  // ---- zero both A buffers; stage h0 at A-rows {0,4,8,12} and x_0 ----
  for (int idx = tid; idx < 2 * ABUF; idx += 512) A_sh[idx] = 0;
  __syncthreads();
  for (int idx = tid; idx < 4 * 256; idx += 512) {
    A_sh[(4 * (idx >> 8)) * ASTR + (idx & 255)] = f2bf(h0[idx & 255]);
  }
  if (tid < 128) {
    const int row = tid >> 5, k = tid & 31;
    A_sh[(4 * row) * ASTR + 256 + k] = f2bf(x[((size_t)(wg * 4 + row) * T_LEN) * 32 + k]);
  }
  __syncthreads();

  const float* xp = x + (size_t)(wg * 4 + ((tid >> 5) & 3)) * T_LEN * 32 + (tid & 31);
  const int akoff = lg * 8;

  for (int t = 0; t < T_LEN; ++t) {
    const int cur = t & 1;
    const short* ArowC = A_sh + cur * ABUF + lr * ASTR;
    short* Anxt = A_sh + (cur ^ 1) * ABUF;

    // finalize previous step's output (hidden under this step's MFMA phase)
    if (t > 0 && w == 0 && l < 4) {
      float s = boutv;
#pragma unroll
      for (int ww = 0; ww < 8; ++ww) s += out_part[cur ^ 1][l][ww];
      out[(size_t)(wg * 4 + l) * T_LEN + (t - 1)] = s;
    }

    // prefetch x_{t+1} (rows 0..3; waves 0,1 only)
    float xval = 0.0f;
    if (tid < 128) {
      const int tn = (t + 1 < T_LEN) ? (t + 1) : (T_LEN - 1);
      xval = xp[(size_t)tn * 32];
    }

    // acc init with biases
    f32x4 acc[4][2];
#pragma unroll
    for (int g = 0; g < 4; ++g) {
#pragma unroll
      for (int nt = 0; nt < 2; ++nt) {
        f32x4 v; v[0] = bias[g][nt]; v[1] = bias[g][nt]; v[2] = bias[g][nt]; v[3] = bias[g][nt];
        acc[g][nt] = v;
      }
    }

    // ---- FG K-loop: register-weight MFMAs ----
#pragma unroll
    for (int ks = 0; ks < 8; ++ks) {
      const bf16x8 a = *reinterpret_cast<const bf16x8*>(ArowC + ks * 32 + akoff);
      acc[0][0] = __builtin_amdgcn_mfma_f32_16x16x32_bf16(a, Bf[ks][0], acc[0][0], 0, 0, 0);
      acc[0][1] = __builtin_amdgcn_mfma_f32_16x16x32_bf16(a, Bf[ks][1], acc[0][1], 0, 0, 0);
      acc[1][0] = __builtin_amdgcn_mfma_f32_16x16x32_bf16(a, Bg[ks][0], acc[1][0], 0, 0, 0);
      acc[1][1] = __builtin_amdgcn_mfma_f32_16x16x32_bf16(a, Bg[ks][1], acc[1][1], 0, 0, 0);
    }

    // ---- i/x MFMA burst ----
    {
      const bf16x8 axv = *reinterpret_cast<const bf16x8*>(ArowC + 256 + akoff);
      acc[3][0] = __builtin_amdgcn_mfma_f32_16x16x32_bf16(axv, Bx[3][0], acc[3][0], 0, 0, 0);
      acc[3][1] = __builtin_amdgcn_mfma_f32_16x16x32_bf16(axv, Bx[3][1], acc[3][1], 0, 0, 0);
      acc[0][0] = __builtin_amdgcn_mfma_f32_16x16x32_bf16(axv, Bx[0][0], acc[0][0], 0, 0, 0);
      acc[0][1] = __builtin_amdgcn_mfma_f32_16x16x32_bf16(axv, Bx[0][1], acc[0][1], 0, 0, 0);
      acc[1][0] = __builtin_amdgcn_mfma_f32_16x16x32_bf16(axv, Bx[1][0], acc[1][0], 0, 0, 0);
      acc[1][1] = __builtin_amdgcn_mfma_f32_16x16x32_bf16(axv, Bx[1][1], acc[1][1], 0, 0, 0);
      acc[2][0] = __builtin_amdgcn_mfma_f32_16x16x32_bf16(axv, Bx[2][0], acc[2][0], 0, 0, 0);
      acc[2][1] = __builtin_amdgcn_mfma_f32_16x16x32_bf16(axv, Bx[2][1], acc[2][1], 0, 0, 0);
    }

    // ---- O K-loop: LDS-weight MFMAs ----
#pragma unroll
    for (int ks = 0; ks < 8; ++ks) {
      const bf16x8 a  = *reinterpret_cast<const bf16x8*>(ArowC + ks * 32 + akoff);
      const bf16x8 b0 = *reinterpret_cast<const bf16x8*>(bo + (ks * 2 + 0) * 512 + l * 8);
      const bf16x8 b1 = *reinterpret_cast<const bf16x8*>(bo + (ks * 2 + 1) * 512 + l * 8);
      acc[2][0] = __builtin_amdgcn_mfma_f32_16x16x32_bf16(a, b0, acc[2][0], 0, 0, 0);
      acc[2][1] = __builtin_amdgcn_mfma_f32_16x16x32_bf16(a, b1, acc[2][1], 0, 0, 0);
    }

    // ---- c-path: 2 gate-sets per lane (row = lg, ch = n0 + nt*16 + lr) ----
    // valid data is element r=0 of each acc (batch row b staged at A-row 4b).
    float tcv[2];
#pragma unroll
    for (int nt = 0; nt < 2; ++nt) {
      const float sf = sigm(acc[0][nt][0]);
      const float tg = tanh_(acc[1][nt][0]);
      const float si = sigm(acc[3][nt][0]);
      const float c  = sf * cst[nt] + si * tg;
      cst[nt] = c;
      tcv[nt] = tanh_(c);
    }

    // ---- o-tail: h, pack, output partial ----
    float po = 0.0f;
    short hpk[2];
#pragma unroll
    for (int nt = 0; nt < 2; ++nt) {
      const float so = sigm(acc[2][nt][0]);
      const float hv = so * tcv[nt];
      hpk[nt] = f2bf(hv);
      po += so * woutv[nt];
    }

    // h-writes into ALTERNATE buffer at A-row 4*lg
    Anxt[(4 * lg) * ASTR + (n0 + lr)]      = hpk[0];
    Anxt[(4 * lg) * ASTR + (n0 + 16 + lr)] = hpk[1];
    // x_{t+1} into ALTERNATE buffer
    if (tid < 128) Anxt[(4 * (tid >> 5)) * ASTR + 256 + (tid & 31)] = f2bf(xval);

    // po reduce over the 16 lr-lanes -> (row = lg, wave w)
#pragma unroll
    for (int mk = 1; mk < 16; mk <<= 1) {
      po += __shfl_xor(po, mk, 64);
    }
    if (lr == 0) out_part[cur][lg][w] = po;

    __syncthreads();  // single per-step barrier
  }

  // final output
  if (w == 0 && l < 4) {
    float s = boutv;
#pragma unroll
    for (int ww = 0; ww < 8; ++ww) s += out_part[(T_LEN - 1) & 1][l][ww];
    out[(size_t)(wg * 4 + l) * T_LEN + (T_LEN - 1)] = s;
  }
}

extern "C" void kernel_launch(void* const* d_in, const int* in_sizes, int n_in,
                              void* d_out, int out_size, void* d_ws, size_t ws_size,
                              hipStream_t stream) {
  const float* x    = (const float*)d_in[0];
  const float* c0   = (const float*)d_in[1];
  const float* h0   = (const float*)d_in[2];
  const float* Wi   = (const float*)d_in[3];
  const float* bi   = (const float*)d_in[4];
  const float* Wfx  = (const float*)d_in[5];
  const float* bfx  = (const float*)d_in[6];
  const float* Wfh  = (const float*)d_in[7];
  const float* bfh  = (const float*)d_in[8];
  const float* Wgx  = (const float*)d_in[9];
  const float* bgx  = (const float*)d_in[10];
  const float* Wgh  = (const float*)d_in[11];
  const float* bgh  = (const float*)d_in[12];
  const float* Wox  = (const float*)d_in[13];
  const float* box_ = (const float*)d_in[14];
  const float* Woh  = (const float*)d_in[15];
  const float* boh  = (const float*)d_in[16];
  const float* Wout = (const float*)d_in[17];
  const float* bout = (const float*)d_in[18];

  ealstm_kernel<<<dim3(32), dim3(512), 0, stream>>>(
      x, c0, h0, Wi, bi, Wfx, bfx, Wfh, bfh,
      Wgx, bgx, Wgh, bgh, Wox, box_, Woh, boh, Wout, bout,
      (float*)d_out);
}

// Round 7
// 4059.923 us; speedup vs baseline: 1.5927x; 1.0002x over previous
//
#include <hip/hip_runtime.h>
#include <hip/hip_bf16.h>

// EA-LSTM for MI355X (gfx950), round 7: two-phase design.
// Phase 1 (precomp_kernel, all CUs): P[b][t][g][pos] bf16 = x-projections +
//   combined biases for f,g,o; sigm(i-pre) for i. 512 MB in d_ws.
// Phase 2 (ealstm_rec, 32 WGs x 256 thr = 4 waves, 1 wave/SIMD, 512-reg budget):
//   wave w owns 64 channels; batch row b staged at A-row 4b so MFMA D r==0
//   lands one gate-set per (lane, nt) with no redistribution.
//   Weights: f,g all 8 K-steps + o K-steps 3..7 in regs; o K-steps 0..2 in LDS.
//   Single merged K-loop: each A-frag read feeds 12 MFMAs.
// Fallback (ws too small): round-6 kernel.

#define T_LEN 2048
#define HD 256

typedef __attribute__((ext_vector_type(8))) short bf16x8;
typedef __attribute__((ext_vector_type(4))) float f32x4;
typedef __attribute__((ext_vector_type(2))) unsigned int u32x2;

#define LOG2E 1.4426950408889634f

__device__ __forceinline__ short f2bf(float f) {
  unsigned u = __float_as_uint(f);
  unsigned r = (u + 0x7fffu + ((u >> 16) & 1u)) >> 16;
  return (short)r;
}

__device__ __forceinline__ bf16x8 loadw8(const float* p) {
  bf16x8 r;
#pragma unroll
  for (int i = 0; i < 8; ++i) r[i] = f2bf(p[i]);
  return r;
}

__device__ __forceinline__ float sigm(float x) {
  float e = __builtin_amdgcn_exp2f(-LOG2E * x);
  return __builtin_amdgcn_rcpf(1.0f + e);
}

// clamp-free tanh: 1 - 2/(e^{2x}+1); saturates to +/-1, NaN-free.
__device__ __forceinline__ float tanh_(float x) {
  float e = __builtin_amdgcn_exp2f((2.0f * LOG2E) * x);
  return 1.0f - 2.0f * __builtin_amdgcn_rcpf(e + 1.0f);
}

// unpack bf16 element nt (0..3) from an 8-byte packed pair of dwords
__device__ __forceinline__ float punp(u32x2 p, int nt) {
  unsigned d = (nt < 2) ? p[0] : p[1];
  unsigned s = (nt & 1) ? (d & 0xffff0000u) : (d << 16);
  return __uint_as_float(s);
}

// ============================ phase 1: precompute ============================
// P layout: element index = ((b*T + t)*4 + g)*256 + (w*64 + lr*4 + nt),
// value: g=0: Wfx@xd+bfx+bfh; g=1: Wgx@xd+bgx+bgh; g=2: Wox@xd+box+boh;
//        g=3: sigm(Wi@xs+bi).  (ch = w*64 + nt*16 + lr)
__global__ __launch_bounds__(256) void precomp_kernel(
    const float* __restrict__ x,
    const float* __restrict__ Wi,  const float* __restrict__ bi,
    const float* __restrict__ Wfx, const float* __restrict__ bfx, const float* __restrict__ bfh,
    const float* __restrict__ Wgx, const float* __restrict__ bgx, const float* __restrict__ bgh,
    const float* __restrict__ Wox, const float* __restrict__ box_, const float* __restrict__ boh,
    unsigned short* __restrict__ P)
{
  const int tid = threadIdx.x;
  const int b   = blockIdx.x;       // 0..127
  const int tc  = blockIdx.y;       // 0..7  (256 t each)
  const int w   = tid >> 6;
  const int lr  = (tid >> 2) & 15;
  const int nt  = tid & 3;
  const int ch  = w * 64 + nt * 16 + lr;

  float wf[8], wg[8], wo[8], wi[24];
#pragma unroll
  for (int d = 0; d < 8; ++d) {
    wf[d] = Wfx[ch * 8 + d];
    wg[d] = Wgx[ch * 8 + d];
    wo[d] = Wox[ch * 8 + d];
  }
#pragma unroll
  for (int d = 0; d < 24; ++d) wi[d] = Wi[ch * 24 + d];
  const float cf = bfx[ch] + bfh[ch];
  const float cg = bgx[ch] + bgh[ch];
  const float co = box_[ch] + boh[ch];
  const float ci = bi[ch];

  __shared__ float xs[32];
  const int t0 = tc * 256;
  for (int t = t0; t < t0 + 256; ++t) {
    __syncthreads();
    if (tid < 32) xs[tid] = x[((size_t)b * T_LEN + t) * 32 + tid];
    __syncthreads();
    float fv = cf, gv = cg, ov = co, iv = ci;
#pragma unroll
    for (int d = 0; d < 8; ++d) {
      fv += xs[d] * wf[d];
      gv += xs[d] * wg[d];
      ov += xs[d] * wo[d];
    }
#pragma unroll
    for (int d = 0; d < 24; ++d) iv += xs[8 + d] * wi[d];
    iv = sigm(iv);
    unsigned short* Pp = P + ((size_t)b * T_LEN + t) * 1024;
    Pp[0 * 256 + tid] = (unsigned short)f2bf(fv);
    Pp[1 * 256 + tid] = (unsigned short)f2bf(gv);
    Pp[2 * 256 + tid] = (unsigned short)f2bf(ov);
    Pp[3 * 256 + tid] = (unsigned short)f2bf(iv);
  }
}

// ============================ phase 2: recurrence ============================
// A tile: 16 rows x 264 cols bf16 (h only). Valid rows at {0,4,8,12}.
#define ASTR 264
#define ABUF (16 * ASTR)

__global__ __launch_bounds__(256, 1) void ealstm_rec(
    const unsigned short* __restrict__ P,
    const float* __restrict__ c0, const float* __restrict__ h0,
    const float* __restrict__ Wfh, const float* __restrict__ Wgh, const float* __restrict__ Woh,
    const float* __restrict__ Wout, const float* __restrict__ bout,
    float* __restrict__ out)
{
  __shared__ __attribute__((aligned(16))) short A_sh[2 * ABUF];          // 16896 B
  __shared__ __attribute__((aligned(16))) short Bo_sh[4 * 3 * 4 * 512];  // 49152 B
  __shared__ float out_part[2][4][4];                                    // 128 B

  const int tid = threadIdx.x;
  const int w   = tid >> 6;   // wave 0..3, owns ch [w*64, w*64+64)
  const int l   = tid & 63;
  const int lr  = l & 15;
  const int lg  = l >> 4;     // activation row = lg (A-row trick)
  const int wg  = blockIdx.x; // 4-row batch block

  // ---- register-resident weights: f,g all K-steps; o K-steps 3..7 ----
  bf16x8 Bf[8][4], Bg[8][4], BoR[5][4];
#pragma unroll
  for (int ks = 0; ks < 8; ++ks) {
#pragma unroll
    for (int nt = 0; nt < 4; ++nt) {
      const int n = w * 64 + nt * 16 + lr;
      const int k = ks * 32 + lg * 8;
      Bf[ks][nt] = loadw8(Wfh + n * HD + k);
      Bg[ks][nt] = loadw8(Wgh + n * HD + k);
    }
  }
#pragma unroll
  for (int ks = 3; ks < 8; ++ks) {
#pragma unroll
    for (int nt = 0; nt < 4; ++nt) {
      const int n = w * 64 + nt * 16 + lr;
      BoR[ks - 3][nt] = loadw8(Woh + n * HD + ks * 32 + lg * 8);
    }
  }
  // ---- LDS-resident: o K-steps 0..2 ----
  short* bo = Bo_sh + w * (3 * 4 * 512);
#pragma unroll
  for (int ks = 0; ks < 3; ++ks) {
#pragma unroll
    for (int nt = 0; nt < 4; ++nt) {
      const int n = w * 64 + nt * 16 + lr;
      bf16x8 fr = loadw8(Woh + n * HD + ks * 32 + lg * 8);
      *reinterpret_cast<bf16x8*>(bo + (ks * 4 + nt) * 512 + l * 8) = fr;
    }
  }

  // ---- Wout, c-state ----
  float woutv[4], cst[4];
#pragma unroll
  for (int nt = 0; nt < 4; ++nt) {
    const int n = w * 64 + nt * 16 + lr;
    woutv[nt] = Wout[n];
    cst[nt]   = c0[n];
  }
  const float boutv = bout[0];

  // ---- zero both A buffers; stage h0 at A-rows {0,4,8,12} ----
  for (int idx = tid; idx < 2 * ABUF; idx += 256) A_sh[idx] = 0;
  __syncthreads();
  for (int idx = tid; idx < 4 * 256; idx += 256) {
    A_sh[(4 * (idx >> 8)) * ASTR + (idx & 255)] = f2bf(h0[idx & 255]);
  }
  __syncthreads();

  // per-lane P pointer: row = wg*4 + lg, lane offset w*64 + lr*4
  const unsigned short* Pl = P + ((size_t)(wg * 4 + lg) * T_LEN) * 1024 + (w * 64 + lr * 4);
  const int akoff = lg * 8;

  // prefetch P for t=0
  u32x2 pc[4], pn[4];
#pragma unroll
  for (int g = 0; g < 4; ++g) {
    pc[g] = *reinterpret_cast<const u32x2*>(Pl + g * 256);
  }

#pragma unroll 2
  for (int t = 0; t < T_LEN; ++t) {
    const int cur = t & 1;
    const short* ArowC = A_sh + cur * ABUF + lr * ASTR;
    short* Anxt = A_sh + (cur ^ 1) * ABUF;

    // prefetch P for t+1 (clamped)
    {
      const int tn = (t + 1 < T_LEN) ? (t + 1) : (T_LEN - 1);
      const unsigned short* Pt = Pl + (size_t)tn * 1024;
#pragma unroll
      for (int g = 0; g < 4; ++g) {
        pn[g] = *reinterpret_cast<const u32x2*>(Pt + g * 256);
      }
    }

    // finalize previous step's output (hidden under this step's MFMA phase)
    if (t > 0 && w == 0 && l < 4) {
      float s = boutv;
#pragma unroll
      for (int ww = 0; ww < 4; ++ww) s += out_part[cur ^ 1][l][ww];
      out[(size_t)(wg * 4 + l) * T_LEN + (t - 1)] = s;
    }

    // accumulators (zero; biases live in P)
    f32x4 acc[3][4];
#pragma unroll
    for (int g = 0; g < 3; ++g) {
#pragma unroll
      for (int nt = 0; nt < 4; ++nt) {
        f32x4 v; v[0] = 0.f; v[1] = 0.f; v[2] = 0.f; v[3] = 0.f;
        acc[g][nt] = v;
      }
    }

    // ---- merged K-loop: 1 A-read -> 12 MFMAs ----
#pragma unroll
    for (int ks = 0; ks < 8; ++ks) {
      const bf16x8 a = *reinterpret_cast<const bf16x8*>(ArowC + ks * 32 + akoff);
#pragma unroll
      for (int nt = 0; nt < 4; ++nt) {
        acc[0][nt] = __builtin_amdgcn_mfma_f32_16x16x32_bf16(a, Bf[ks][nt], acc[0][nt], 0, 0, 0);
      }
#pragma unroll
      for (int nt = 0; nt < 4; ++nt) {
        acc[1][nt] = __builtin_amdgcn_mfma_f32_16x16x32_bf16(a, Bg[ks][nt], acc[1][nt], 0, 0, 0);
      }
      if (ks < 3) {
#pragma unroll
        for (int nt = 0; nt < 4; ++nt) {
          const bf16x8 b = *reinterpret_cast<const bf16x8*>(bo + (ks * 4 + nt) * 512 + l * 8);
          acc[2][nt] = __builtin_amdgcn_mfma_f32_16x16x32_bf16(a, b, acc[2][nt], 0, 0, 0);
        }
      } else {
#pragma unroll
        for (int nt = 0; nt < 4; ++nt) {
          acc[2][nt] = __builtin_amdgcn_mfma_f32_16x16x32_bf16(a, BoR[ks - 3][nt], acc[2][nt], 0, 0, 0);
        }
      }
    }

    // ---- activations: 4 gate-sets per lane (row = lg, ch = w*64 + nt*16 + lr) ----
    float po = 0.0f;
#pragma unroll
    for (int nt = 0; nt < 4; ++nt) {
      const float fpre = acc[0][nt][0] + punp(pc[0], nt);
      const float gpre = acc[1][nt][0] + punp(pc[1], nt);
      const float opre = acc[2][nt][0] + punp(pc[2], nt);
      const float iv   = punp(pc[3], nt);  // sigmoid already applied
      const float sf = sigm(fpre);
      const float tg = tanh_(gpre);
      const float so = sigm(opre);
      const float c  = sf * cst[nt] + iv * tg;
      cst[nt] = c;
      const float hv = so * tanh_(c);
      Anxt[(4 * lg) * ASTR + (w * 64 + nt * 16 + lr)] = f2bf(hv);
      po += so * woutv[nt];
    }

    // po reduce over the 16 lr-lanes -> (row = lg, wave w)
#pragma unroll
    for (int mk = 1; mk < 16; mk <<= 1) {
      po += __shfl_xor(po, mk, 64);
    }
    if (lr == 0) out_part[cur][lg][w] = po;

    // roll P prefetch
#pragma unroll
    for (int g = 0; g < 4; ++g) pc[g] = pn[g];

    __syncthreads();  // single per-step barrier
  }

  // final output
  if (w == 0 && l < 4) {
    float s = boutv;
#pragma unroll
    for (int ww = 0; ww < 4; ++ww) s += out_part[(T_LEN - 1) & 1][l][ww];
    out[(size_t)(wg * 4 + l) * T_LEN + (T_LEN - 1)] = s;
  }
}

// ============================ fallback: round-6 kernel ============================
#define FASTR 296
#define FABUF (16 * FASTR)

__global__ __launch_bounds__(512, 2) void ealstm_fallback(
    const float* __restrict__ x, const float* __restrict__ c0, const float* __restrict__ h0,
    const float* __restrict__ Wi, const float* __restrict__ bi,
    const float* __restrict__ Wfx, const float* __restrict__ bfx,
    const float* __restrict__ Wfh, const float* __restrict__ bfh,
    const float* __restrict__ Wgx, const float* __restrict__ bgx,
    const float* __restrict__ Wgh, const float* __restrict__ bgh,
    const float* __restrict__ Wox, const float* __restrict__ box_,
    const float* __restrict__ Woh, const float* __restrict__ boh,
    const float* __restrict__ Wout, const float* __restrict__ bout,
    float* __restrict__ out)
{
  __shared__ __attribute__((aligned(16))) short A_sh[2 * FABUF];
  __shared__ __attribute__((aligned(16))) short Bo_sh[8 * 16 * 512];
  __shared__ float out_part[2][4][8];

  const int tid = threadIdx.x;
  const int w   = tid >> 6;
  const int l   = tid & 63;
  const int lr  = l & 15;
  const int lg  = l >> 4;
  const int n0  = w * 32;
  const int wg  = blockIdx.x;

  bf16x8 Bf[8][2], Bg[8][2], Bx[4][2];
#pragma unroll
  for (int ks = 0; ks < 8; ++ks) {
#pragma unroll
    for (int nt = 0; nt < 2; ++nt) {
      const int n = n0 + nt * 16 + lr;
      const int k = ks * 32 + lg * 8;
      Bf[ks][nt] = loadw8(Wfh + n * HD + k);
      Bg[ks][nt] = loadw8(Wgh + n * HD + k);
    }
  }
  {
    bf16x8 z = (bf16x8)(short)0;
    const float* WxArr[3] = {Wfx, Wgx, Wox};
#pragma unroll
    for (int nt = 0; nt < 2; ++nt) {
      const int n = n0 + nt * 16 + lr;
#pragma unroll
      for (int g = 0; g < 3; ++g) {
        Bx[g][nt] = (lg == 0) ? loadw8(WxArr[g] + n * 8) : z;
      }
      Bx[3][nt] = (lg >= 1) ? loadw8(Wi + n * 24 + (lg - 1) * 8) : z;
    }
  }

  short* bo = Bo_sh + w * (16 * 512);
#pragma unroll
  for (int ks = 0; ks < 8; ++ks) {
#pragma unroll
    for (int nt = 0; nt < 2; ++nt) {
      const int n = n0 + nt * 16 + lr;
      bf16x8 fr = loadw8(Woh + n * HD + ks * 32 + lg * 8);
      *reinterpret_cast<bf16x8*>(bo + (ks * 2 + nt) * 512 + l * 8) = fr;
    }
  }

  float bias[4][2], woutv[2], cst[2];
#pragma unroll
  for (int nt = 0; nt < 2; ++nt) {
    const int n = n0 + nt * 16 + lr;
    bias[0][nt] = bfx[n] + bfh[n];
    bias[1][nt] = bgx[n] + bgh[n];
    bias[2][nt] = box_[n] + boh[n];
    bias[3][nt] = bi[n];
    woutv[nt] = Wout[n];
    cst[nt] = c0[n];
  }
  const float boutv = bout[0];

  for (int idx = tid; idx < 2 * FABUF; idx += 512) A_sh[idx] = 0;
  __syncthreads();
  for (int idx = tid; idx < 4 * 256; idx += 512) {
    A_sh[(4 * (idx >> 8)) * FASTR + (idx & 255)] = f2bf(h0[idx & 255]);
  }
  if (tid < 128) {
    const int row = tid >> 5, k = tid & 31;
    A_sh[(4 * row) * FASTR + 256 + k] = f2bf(x[((size_t)(wg * 4 + row) * T_LEN) * 32 + k]);
  }
  __syncthreads();

  const float* xp = x + (size_t)(wg * 4 + ((tid >> 5) & 3)) * T_LEN * 32 + (tid & 31);
  const int akoff = lg * 8;

  for (int t = 0; t < T_LEN; ++t) {
    const int cur = t & 1;
    const short* ArowC = A_sh + cur * FABUF + lr * FASTR;
    short* Anxt = A_sh + (cur ^ 1) * FABUF;

    if (t > 0 && w == 0 && l < 4) {
      float s = boutv;
#pragma unroll
      for (int ww = 0; ww < 8; ++ww) s += out_part[cur ^ 1][l][ww];
      out[(size_t)(wg * 4 + l) * T_LEN + (t - 1)] = s;
    }

    float xval = 0.0f;
    if (tid < 128) {
      const int tn = (t + 1 < T_LEN) ? (t + 1) : (T_LEN - 1);
      xval = xp[(size_t)tn * 32];
    }

    f32x4 acc[4][2];
#pragma unroll
    for (int g = 0; g < 4; ++g) {
#pragma unroll
      for (int nt = 0; nt < 2; ++nt) {
        f32x4 v; v[0] = bias[g][nt]; v[1] = bias[g][nt]; v[2] = bias[g][nt]; v[3] = bias[g][nt];
        acc[g][nt] = v;
      }
    }

#pragma unroll
    for (int ks = 0; ks < 8; ++ks) {
      const bf16x8 a = *reinterpret_cast<const bf16x8*>(ArowC + ks * 32 + akoff);
      acc[0][0] = __builtin_amdgcn_mfma_f32_16x16x32_bf16(a, Bf[ks][0], acc[0][0], 0, 0, 0);
      acc[0][1] = __builtin_amdgcn_mfma_f32_16x16x32_bf16(a, Bf[ks][1], acc[0][1], 0, 0, 0);
      acc[1][0] = __builtin_amdgcn_mfma_f32_16x16x32_bf16(a, Bg[ks][0], acc[1][0], 0, 0, 0);
      acc[1][1] = __builtin_amdgcn_mfma_f32_16x16x32_bf16(a, Bg[ks][1], acc[1][1], 0, 0, 0);
    }
    {
      const bf16x8 axv = *reinterpret_cast<const bf16x8*>(ArowC + 256 + akoff);
      acc[3][0] = __builtin_amdgcn_mfma_f32_16x16x32_bf16(axv, Bx[3][0], acc[3][0], 0, 0, 0);
      acc[3][1] = __builtin_amdgcn_mfma_f32_16x16x32_bf16(axv, Bx[3][1], acc[3][1], 0, 0, 0);
      acc[0][0] = __builtin_amdgcn_mfma_f32_16x16x32_bf16(axv, Bx[0][0], acc[0][0], 0, 0, 0);
      acc[0][1] = __builtin_amdgcn_mfma_f32_16x16x32_bf16(axv, Bx[0][1], acc[0][1], 0, 0, 0);
      acc[1][0] = __builtin_amdgcn_mfma_f32_16x16x32_bf16(axv, Bx[1][0], acc[1][0], 0, 0, 0);
      acc[1][1] = __builtin_amdgcn_mfma_f32_16x16x32_bf16(axv, Bx[1][1], acc[1][1], 0, 0, 0);
      acc[2][0] = __builtin_amdgcn_mfma_f32_16x16x32_bf16(axv, Bx[2][0], acc[2][0], 0, 0, 0);
      acc[2][1] = __builtin_amdgcn_mfma_f32_16x16x32_bf16(axv, Bx[2][1], acc[2][1], 0, 0, 0);
    }
#pragma unroll
    for (int ks = 0; ks < 8; ++ks) {
      const bf16x8 a  = *reinterpret_cast<const bf16x8*>(ArowC + ks * 32 + akoff);
      const bf16x8 b0 = *reinterpret_cast<const bf16x8*>(bo + (ks * 2 + 0) * 512 + l * 8);
      const bf16x8 b1 = *reinterpret_cast<const bf16x8*>(bo + (ks * 2 + 1) * 512 + l * 8);
      acc[2][0] = __builtin_amdgcn_mfma_f32_16x16x32_bf16(a, b0, acc[2][0], 0, 0, 0);
      acc[2][1] = __builtin_amdgcn_mfma_f32_16x16x32_bf16(a, b1, acc[2][1], 0, 0, 0);
    }

    float tcv[2];
#pragma unroll
    for (int nt = 0; nt < 2; ++nt) {
      const float sf = sigm(acc[0][nt][0]);
      const float tg = tanh_(acc[1][nt][0]);
      const float si = sigm(acc[3][nt][0]);
      const float c  = sf * cst[nt] + si * tg;
      cst[nt] = c;
      tcv[nt] = tanh_(c);
    }

    float po = 0.0f;
    short hpk[2];
#pragma unroll
    for (int nt = 0; nt < 2; ++nt) {
      const float so = sigm(acc[2][nt][0]);
      const float hv = so * tcv[nt];
      hpk[nt] = f2bf(hv);
      po += so * woutv[nt];
    }

    Anxt[(4 * lg) * FASTR + (n0 + lr)]      = hpk[0];
    Anxt[(4 * lg) * FASTR + (n0 + 16 + lr)] = hpk[1];
    if (tid < 128) Anxt[(4 * (tid >> 5)) * FASTR + 256 + (tid & 31)] = f2bf(xval);

#pragma unroll
    for (int mk = 1; mk < 16; mk <<= 1) {
      po += __shfl_xor(po, mk, 64);
    }
    if (lr == 0) out_part[cur][lg][w] = po;

    __syncthreads();
  }

  if (w == 0 && l < 4) {
    float s = boutv;
#pragma unroll
    for (int ww = 0; ww < 8; ++ww) s += out_part[(T_LEN - 1) & 1][l][ww];
    out[(size_t)(wg * 4 + l) * T_LEN + (T_LEN - 1)] = s;
  }
}

extern "C" void kernel_launch(void* const* d_in, const int* in_sizes, int n_in,
                              void* d_out, int out_size, void* d_ws, size_t ws_size,
                              hipStream_t stream) {
  const float* x    = (const float*)d_in[0];
  const float* c0   = (const float*)d_in[1];
  const float* h0   = (const float*)d_in[2];
  const float* Wi   = (const float*)d_in[3];
  const float* bi   = (const float*)d_in[4];
  const float* Wfx  = (const float*)d_in[5];
  const float* bfx  = (const float*)d_in[6];
  const float* Wfh  = (const float*)d_in[7];
  const float* bfh  = (const float*)d_in[8];
  const float* Wgx  = (const float*)d_in[9];
  const float* bgx  = (const float*)d_in[10];
  const float* Wgh  = (const float*)d_in[11];
  const float* bgh  = (const float*)d_in[12];
  const float* Wox  = (const float*)d_in[13];
  const float* box_ = (const float*)d_in[14];
  const float* Woh  = (const float*)d_in[15];
  const float* boh  = (const float*)d_in[16];
  const float* Wout = (const float*)d_in[17];
  const float* bout = (const float*)d_in[18];

  const size_t pbytes = (size_t)128 * T_LEN * 1024 * sizeof(unsigned short);  // 512 MiB
  if (ws_size >= pbytes) {
    unsigned short* P = (unsigned short*)d_ws;
    precomp_kernel<<<dim3(128, 8), dim3(256), 0, stream>>>(
        x, Wi, bi, Wfx, bfx, bfh, Wgx, bgx, bgh, Wox, box_, boh, P);
    ealstm_rec<<<dim3(32), dim3(256), 0, stream>>>(
        P, c0, h0, Wfh, Wgh, Woh, Wout, bout, (float*)d_out);
  } else {
    ealstm_fallback<<<dim3(32), dim3(512), 0, stream>>>(
        x, c0, h0, Wi, bi, Wfx, bfx, Wfh, bfh,
        Wgx, bgx, Wgh, bgh, Wox, box_, Woh, boh, Wout, bout,
        (float*)d_out);
  }
}